// Round 5
// baseline (462.765 us; speedup 1.0000x reference)
//
#include <hip/hip_runtime.h>
#include <hip/hip_bf16.h>
#include <math.h>
#include <stdint.h>

typedef __attribute__((ext_vector_type(4))) float floatx4;
typedef __attribute__((ext_vector_type(8))) short shortx8;
typedef __attribute__((ext_vector_type(8))) unsigned short ushortx8;
typedef __attribute__((ext_vector_type(4))) unsigned short ushortx4;

#define BS_CAND 4096   // B*S
#define HDIM    1024
#define MSLOTS  8192
#define THRESH  64.0f
#define PV_SPLIT 4

__device__ __forceinline__ unsigned short f2b_bits(float f) {
    __hip_bfloat16 b = __float2bfloat16(f);
    return *(unsigned short*)&b;
}
__device__ __forceinline__ float b2f_bits(unsigned short u) {
    return __uint_as_float(((unsigned)u) << 16);
}

// ---------------- reduction helpers (blockDim == 256) ----------------
__device__ __forceinline__ float blockReduceSum(float x) {
    __shared__ float red[4];
    #pragma unroll
    for (int o = 32; o > 0; o >>= 1) x += __shfl_down(x, o, 64);
    int lane = threadIdx.x & 63, w = threadIdx.x >> 6;
    if (lane == 0) red[w] = x;
    __syncthreads();
    float s = red[0] + red[1] + red[2] + red[3];
    __syncthreads();
    return s;
}

// ---------------- surprise = 2*||row||_2 ----------------
__global__ __launch_bounds__(256) void surprise_k(const float* __restrict__ h,
                                                  float* __restrict__ sur) {
    int row = blockIdx.x;
    const float* p = h + (size_t)row * HDIM;
    float s = 0.f;
    for (int i = threadIdx.x; i < HDIM; i += 256) { float v = p[i]; s += v * v; }
    float tot = blockReduceSum(s);
    if (threadIdx.x == 0) sur[row] = 2.0f * sqrtf(tot);
}

// ---------------- slot keys = imp + 1e-6*noise; row_src = -1; rowsum = 0 -----
__global__ __launch_bounds__(256) void slot_keys_k(const float* __restrict__ imp,
                                                   const float* __restrict__ noi,
                                                   float* __restrict__ keys,
                                                   int* __restrict__ row_src,
                                                   float* __restrict__ rowsum) {
    int i = blockIdx.x * 256 + threadIdx.x;
    keys[i] = imp[i] + noi[i] * 1e-6f;
    row_src[i] = -1;
    if (i < BS_CAND) rowsum[i] = 0.f;
}

// ---------------- rank by counting: one BLOCK per element ----------------
// DESC=1: rank among descending order; DESC=0: ascending. Stable (ties by index).
template <int DESC>
__global__ __launch_bounds__(256) void rank_k(const float* __restrict__ keys,
                                              int n, int* __restrict__ order) {
    int i = blockIdx.x;
    float ki = keys[i];
    float cnt = 0.f;
    for (int j = threadIdx.x; j < n; j += 256) {
        float kj = keys[j];
        bool before = DESC ? (kj > ki) : (kj < ki);
        cnt += (before || (kj == ki && j < i)) ? 1.f : 0.f;
    }
    float r = blockReduceSum(cnt);
    if (threadIdx.x == 0) order[(int)r] = i;
}

// ---------------- scatter: rank-i candidate -> rank-i least-important slot ----
__global__ __launch_bounds__(256) void scatter_k(const int* __restrict__ cand_order,
                                                 const int* __restrict__ slot_order,
                                                 const float* __restrict__ sur,
                                                 int* __restrict__ row_src) {
    int i = blockIdx.x * 256 + threadIdx.x;   // i < BS_CAND
    int c = cand_order[i];
    if (sur[c] > THRESH) row_src[slot_order[i]] = c;
}

// ---------------- fp32 -> bf16 flat convert, 4 elems/thread ----------------
__global__ __launch_bounds__(256) void f2b_k(const float* __restrict__ in,
                                             __hip_bfloat16* __restrict__ out, int n4) {
    int i = blockIdx.x * 256 + threadIdx.x;
    if (i < n4) {
        float4 v = ((const float4*)in)[i];
        ushortx4 o;
        o.x = f2b_bits(v.x); o.y = f2b_bits(v.y);
        o.z = f2b_bits(v.z); o.w = f2b_bits(v.w);
        ((ushortx4*)out)[i] = o;
    }
}

// ---------------- build updated buffer (bf16), 4 elems/thread -------------
__global__ __launch_bounds__(256) void build_b_k(const float* __restrict__ mem,
                                                 const float* __restrict__ hid,
                                                 const int* __restrict__ src,
                                                 __hip_bfloat16* __restrict__ B) {
    int m = blockIdx.x;
    int s = src[m];
    const float4* r = (const float4*)((s < 0) ? (mem + (size_t)m * HDIM)
                                              : (hid + (size_t)s * HDIM));
    float4 v = r[threadIdx.x];                 // HDIM/4 == 256 == blockDim
    ushortx4 o;
    o.x = f2b_bits(v.x); o.y = f2b_bits(v.y);
    o.z = f2b_bits(v.z); o.w = f2b_bits(v.w);
    ((ushortx4*)(B + (size_t)m * HDIM))[threadIdx.x] = o;
}

// ---------------- bf16 transpose [R][C] -> [C][R] ----------------
__global__ __launch_bounds__(256) void transpose_k(const __hip_bfloat16* __restrict__ in,
                                                   __hip_bfloat16* __restrict__ out,
                                                   int R, int C) {
    __shared__ __hip_bfloat16 t[64][65];
    int cb = blockIdx.x * 64, rb = blockIdx.y * 64;
    int tx = threadIdx.x & 63, ty = threadIdx.x >> 6;
    #pragma unroll
    for (int k = 0; k < 16; k++) {
        int r = ty * 16 + k;
        t[r][tx] = in[(size_t)(rb + r) * C + cb + tx];
    }
    __syncthreads();
    #pragma unroll
    for (int k = 0; k < 16; k++) {
        int c = ty * 16 + k;
        out[(size_t)(cb + c) * R + rb + tx] = t[tx][c];
    }
}

// ---------------- async global->LDS helper ----------------
__device__ __forceinline__ void load_lds16(const __hip_bfloat16* g, __hip_bfloat16* l) {
    __builtin_amdgcn_global_load_lds(
        (const __attribute__((address_space(1))) void*)g,
        (__attribute__((address_space(3))) void*)l, 16, 0, 0);
}

// ---------------- BT-GEMM: C[M,N] = A[M,K] * Bt[N,K]^T  (m97 structure) ----------
// SWAP=1: bm from blockIdx.x, bn from blockIdx.y (XCD locality: all bn-blocks of
//         one bm get the same flat-id mod 8 -> same XCD L2 caches the A chunk).
// EPI 0: outF[z*M*N + idx] = acc * scale       (fp32 out, split-K partial)
// EPI 1: outH[idx] = bf16(acc + bias[col])     (bf16 out)
// EPI 3: outH[idx] = bf16(exp(acc*scale)), rowsum[row] += sum (fused softmax num.)
template <int EPI, int SWAP>
__global__ __launch_bounds__(256) void gemm_bt(const __hip_bfloat16* __restrict__ A,
                                               const __hip_bfloat16* __restrict__ Bt,
                                               float* __restrict__ outF,
                                               __hip_bfloat16* __restrict__ outH,
                                               const float* __restrict__ bias,
                                               float* __restrict__ rowsum,
                                               int M, int N, int K, int ksplit,
                                               float scale) {
    __shared__ alignas(16) __hip_bfloat16 Asm[128 * 64];
    __shared__ alignas(16) __hip_bfloat16 Bsm[128 * 64];
    const int tid = threadIdx.x;
    const int wave = tid >> 6, lane = tid & 63;
    const int bm = SWAP ? blockIdx.x : blockIdx.y;
    const int bn = SWAP ? blockIdx.y : blockIdx.x;
    const int kb = blockIdx.z * ksplit, ke = kb + ksplit;
    const int wr = (wave >> 1) * 64, wc = (wave & 1) * 64;
    const int lm = lane & 15, lq = lane >> 4;

    floatx4 acc[4][4];
    #pragma unroll
    for (int i = 0; i < 4; i++)
        #pragma unroll
        for (int j = 0; j < 4; j++) acc[i][j] = {0.f, 0.f, 0.f, 0.f};

    const __hip_bfloat16* Abase = A + (size_t)bm * 128 * K;
    const __hip_bfloat16* Bbase = Bt + (size_t)bn * 128 * K;

    for (int k0 = kb; k0 < ke; k0 += 64) {
        #pragma unroll
        for (int t = 0; t < 4; t++) {
            int c = (wave * 4 + t) * 64 + lane;       // 16B chunk index
            int row = c >> 3, col = (c & 7) * 8;
            load_lds16(Abase + (size_t)row * K + k0 + col, &Asm[(wave * 4 + t) * 512]);
        }
        #pragma unroll
        for (int t = 0; t < 4; t++) {
            int c = (wave * 4 + t) * 64 + lane;
            int row = c >> 3, col = (c & 7) * 8;
            load_lds16(Bbase + (size_t)row * K + k0 + col, &Bsm[(wave * 4 + t) * 512]);
        }
        __syncthreads();
        #pragma unroll
        for (int ks = 0; ks < 2; ks++) {
            shortx8 af[4], bfr[4];
            #pragma unroll
            for (int i = 0; i < 4; i++)
                af[i] = *(const shortx8*)(&Asm[(wr + i * 16 + lm) * 64 + ks * 32 + lq * 8]);
            #pragma unroll
            for (int j = 0; j < 4; j++)
                bfr[j] = *(const shortx8*)(&Bsm[(wc + j * 16 + lm) * 64 + ks * 32 + lq * 8]);
            #pragma unroll
            for (int i = 0; i < 4; i++)
                #pragma unroll
                for (int j = 0; j < 4; j++)
                    acc[i][j] = __builtin_amdgcn_mfma_f32_16x16x32_bf16(af[i], bfr[j],
                                                                        acc[i][j], 0, 0, 0);
        }
        __syncthreads();
    }

    if (EPI == 3) {
        // E = bf16(exp(S)); rowsum[row] += sum of rounded E values
        #pragma unroll
        for (int i = 0; i < 4; i++) {
            int grow0 = bm * 128 + wr + i * 16 + lq * 4;
            #pragma unroll
            for (int r = 0; r < 4; r++) {
                float rs = 0.f;
                #pragma unroll
                for (int j = 0; j < 4; j++) {
                    int gcol = bn * 128 + wc + j * 16 + lm;
                    float e = __expf(acc[i][j][r] * scale);
                    unsigned short eb = f2b_bits(e);
                    ((unsigned short*)outH)[(size_t)(grow0 + r) * N + gcol] = eb;
                    rs += b2f_bits(eb);
                }
                rs += __shfl_xor(rs, 1, 64);
                rs += __shfl_xor(rs, 2, 64);
                rs += __shfl_xor(rs, 4, 64);
                rs += __shfl_xor(rs, 8, 64);
                if (lm == 0) atomicAdd(&rowsum[grow0 + r], rs);
            }
        }
    } else {
        float* outFz = outF + (size_t)blockIdx.z * M * N;
        #pragma unroll
        for (int i = 0; i < 4; i++) {
            int grow0 = bm * 128 + wr + i * 16 + lq * 4;
            #pragma unroll
            for (int j = 0; j < 4; j++) {
                int gcol = bn * 128 + wc + j * 16 + lm;
                #pragma unroll
                for (int r = 0; r < 4; r++) {
                    float v = acc[i][j][r];
                    size_t idx = (size_t)(grow0 + r) * N + gcol;
                    if (EPI == 0)      outFz[idx] = v * scale;
                    else               outH[idx] = __float2bfloat16(v + bias[gcol]);
                }
            }
        }
    }
}

// ---------------- sum 4 fp32 partials, scale by 1/rowsum -> out ----------------
__global__ __launch_bounds__(256) void reduce4_k(const float4* __restrict__ p,
                                                 const float* __restrict__ rowsum,
                                                 float4* __restrict__ out, int n4) {
    int i = blockIdx.x * 256 + threadIdx.x;
    if (i < n4) {
        float inv = 1.f / rowsum[i >> 8];          // HDIM/4 = 256 float4 per row
        float4 a = p[i], b = p[i + n4], c = p[i + 2 * n4], d = p[i + 3 * n4];
        float4 o;
        o.x = ((a.x + b.x) + (c.x + d.x)) * inv;
        o.y = ((a.y + b.y) + (c.y + d.y)) * inv;
        o.z = ((a.z + b.z) + (c.z + d.z)) * inv;
        o.w = ((a.w + b.w) + (c.w + d.w)) * inv;
        out[i] = o;
    }
}

// ---------------- launch ----------------
extern "C" void kernel_launch(void* const* d_in, const int* in_sizes, int n_in,
                              void* d_out, int out_size, void* d_ws, size_t ws_size,
                              hipStream_t stream) {
    const float* hidden = (const float*)d_in[0];   // [2,2048,1024]
    const float* membuf = (const float*)d_in[1];   // [8192,1024]
    const float* imp    = (const float*)d_in[2];   // [8192]
    const float* Wq     = (const float*)d_in[3];   // [1024,1024]
    const float* bq     = (const float*)d_in[4];   // [1024]
    const float* Wk     = (const float*)d_in[5];   // [1024,1024]
    const float* bk     = (const float*)d_in[6];   // [1024]
    const float* noise  = (const float*)d_in[7];   // [8192]

    char* ws = (char*)d_ws;
    size_t off = 0;
    auto alloc = [&](size_t bytes) -> void* {
        void* p = ws + off;
        off += (bytes + 255) & ~(size_t)255;
        return p;
    };
    // --- persistent region (front) ---
    float*          surprise = (float*)alloc(BS_CAND * 4);
    float*          skeys    = (float*)alloc(MSLOTS * 4);
    float*          rowsum   = (float*)alloc(BS_CAND * 4);
    int*            cand_ord = (int*)alloc(BS_CAND * 4);
    int*            slot_ord = (int*)alloc(MSLOTS * 4);
    int*            row_src  = (int*)alloc(MSLOTS * 4);
    __hip_bfloat16* Wqbf = (__hip_bfloat16*)alloc((size_t)HDIM * HDIM * 2);    // 2 MB
    __hip_bfloat16* Wkbf = (__hip_bfloat16*)alloc((size_t)HDIM * HDIM * 2);    // 2 MB
    __hip_bfloat16* BbfT = (__hip_bfloat16*)alloc((size_t)HDIM * MSLOTS * 2);  // 16 MB
    // --- Sbf region (64 MB), overlaid with Hbf (8 MB) + Bbf (16 MB) which die
    // before the scores GEMM writes Sbf ---
    size_t s_base = off;
    __hip_bfloat16* Sbf = (__hip_bfloat16*)(ws + s_base);                      // 64 MB
    __hip_bfloat16* Hbf = (__hip_bfloat16*)(ws + s_base);                      //  8 MB
    __hip_bfloat16* Bbf = (__hip_bfloat16*)(ws + s_base + (size_t)BS_CAND * HDIM * 2);
    off = s_base + ((size_t)BS_CAND * MSLOTS * 2 + 255) & ~(size_t)255;
    // --- tail region: qbf+mkbf live until scores GEMM; PV partials (64 MB)
    // overlay them afterwards ---
    size_t t_base = off;
    __hip_bfloat16* qbf  = (__hip_bfloat16*)alloc((size_t)BS_CAND * HDIM * 2); // 8 MB
    __hip_bfloat16* mkbf = (__hip_bfloat16*)alloc((size_t)MSLOTS * HDIM * 2);  // 16 MB
    float*          part = (float*)(ws + t_base);       // 4 x 16 MB fp32 partials
    // peak usage = t_base + 64 MB  (~148 MB total)

    // 1) selection phase
    surprise_k<<<BS_CAND, 256, 0, stream>>>(hidden, surprise);
    slot_keys_k<<<MSLOTS / 256, 256, 0, stream>>>(imp, noise, skeys, row_src, rowsum);
    rank_k<1><<<BS_CAND, 256, 0, stream>>>(surprise, BS_CAND, cand_ord);
    rank_k<0><<<MSLOTS, 256, 0, stream>>>(skeys, MSLOTS, slot_ord);
    scatter_k<<<BS_CAND / 256, 256, 0, stream>>>(cand_ord, slot_ord, surprise, row_src);

    // 2) bf16 materialization
    f2b_k<<<(BS_CAND * HDIM / 4) / 256, 256, 0, stream>>>(hidden, Hbf, BS_CAND * HDIM / 4);
    f2b_k<<<(HDIM * HDIM / 4) / 256, 256, 0, stream>>>(Wq, Wqbf, HDIM * HDIM / 4);
    f2b_k<<<(HDIM * HDIM / 4) / 256, 256, 0, stream>>>(Wk, Wkbf, HDIM * HDIM / 4);
    build_b_k<<<MSLOTS, 256, 0, stream>>>(membuf, hidden, row_src, Bbf);
    transpose_k<<<dim3(HDIM / 64, MSLOTS / 64), 256, 0, stream>>>(Bbf, BbfT, MSLOTS, HDIM);

    // 3) q = hidden @ Wq^T + bq   -> bf16 [4096,1024]   (Hbf dies after this)
    gemm_bt<1, 0><<<dim3(HDIM / 128, BS_CAND / 128), 256, 0, stream>>>(
        Hbf, Wqbf, nullptr, qbf, bq, nullptr, BS_CAND, HDIM, HDIM, HDIM, 1.f);
    // 4) mk = newbuf @ Wk^T + bk  -> bf16 [8192,1024]   (Bbf dies after this)
    gemm_bt<1, 0><<<dim3(HDIM / 128, MSLOTS / 128), 256, 0, stream>>>(
        Bbf, Wkbf, nullptr, mkbf, bk, nullptr, MSLOTS, HDIM, HDIM, HDIM, 1.f);
    // 5) E = bf16(exp((q @ mk^T)/32)), rowsum = row sums  — fused softmax numerator
    //    (no max-subtraction needed: |S| <= ~3, exp safely in fp32 range)
    gemm_bt<3, 0><<<dim3(MSLOTS / 128, BS_CAND / 128), 256, 0, stream>>>(
        qbf, mkbf, nullptr, Sbf, nullptr, rowsum, BS_CAND, MSLOTS, HDIM, HDIM, 0.03125f);
    // 6) split-K PV: partial[z] = E @ newbuf over K-chunk z  (overlays qbf/mkbf)
    //    SWAP=1: bm on grid.x so all bn-blocks of one bm share an XCD (L2 reuse)
    gemm_bt<0, 1><<<dim3(BS_CAND / 128, HDIM / 128, PV_SPLIT), 256, 0, stream>>>(
        Sbf, BbfT, part, nullptr, nullptr, nullptr, BS_CAND, HDIM, MSLOTS,
        MSLOTS / PV_SPLIT, 1.f);
    // 7) out = (sum of 4 partials) / rowsum   -> fp32 [4096,1024]
    reduce4_k<<<(BS_CAND * HDIM / 4) / 256, 256, 0, stream>>>(
        (const float4*)part, rowsum, (float4*)d_out, BS_CAND * HDIM / 4);
}

// Round 6
// 440.165 us; speedup vs baseline: 1.0513x; 1.0513x over previous
//
#include <hip/hip_runtime.h>
#include <hip/hip_bf16.h>
#include <math.h>
#include <stdint.h>

typedef __attribute__((ext_vector_type(4))) float floatx4;
typedef __attribute__((ext_vector_type(8))) short shortx8;
typedef __attribute__((ext_vector_type(8))) unsigned short ushortx8;
typedef __attribute__((ext_vector_type(4))) unsigned short ushortx4;

#define BS_CAND 4096   // B*S
#define HDIM    1024
#define MSLOTS  8192
#define THRESH  64.0f
#define PV_SPLIT 4

__device__ __forceinline__ unsigned short f2b_bits(float f) {
    __hip_bfloat16 b = __float2bfloat16(f);
    return *(unsigned short*)&b;
}
__device__ __forceinline__ float b2f_bits(unsigned short u) {
    return __uint_as_float(((unsigned)u) << 16);
}

// ---------------- reduction helpers (blockDim == 256) ----------------
__device__ __forceinline__ float blockReduceSum(float x) {
    __shared__ float red[4];
    #pragma unroll
    for (int o = 32; o > 0; o >>= 1) x += __shfl_down(x, o, 64);
    int lane = threadIdx.x & 63, w = threadIdx.x >> 6;
    if (lane == 0) red[w] = x;
    __syncthreads();
    float s = red[0] + red[1] + red[2] + red[3];
    __syncthreads();
    return s;
}

// ---------------- surprise = 2*||row||_2 ----------------
__global__ __launch_bounds__(256) void surprise_k(const float* __restrict__ h,
                                                  float* __restrict__ sur) {
    int row = blockIdx.x;
    const float* p = h + (size_t)row * HDIM;
    float s = 0.f;
    for (int i = threadIdx.x; i < HDIM; i += 256) { float v = p[i]; s += v * v; }
    float tot = blockReduceSum(s);
    if (threadIdx.x == 0) sur[row] = 2.0f * sqrtf(tot);
}

// ---------------- slot keys = imp + 1e-6*noise; row_src = -1 ----------------
__global__ __launch_bounds__(256) void slot_keys_k(const float* __restrict__ imp,
                                                   const float* __restrict__ noi,
                                                   float* __restrict__ keys,
                                                   int* __restrict__ row_src) {
    int i = blockIdx.x * 256 + threadIdx.x;
    keys[i] = imp[i] + noi[i] * 1e-6f;
    row_src[i] = -1;
}

// ---------------- rank by counting: one BLOCK per element ----------------
// DESC=1: rank among descending order; DESC=0: ascending. Stable (ties by index).
template <int DESC>
__global__ __launch_bounds__(256) void rank_k(const float* __restrict__ keys,
                                              int n, int* __restrict__ order) {
    int i = blockIdx.x;
    float ki = keys[i];
    float cnt = 0.f;
    for (int j = threadIdx.x; j < n; j += 256) {
        float kj = keys[j];
        bool before = DESC ? (kj > ki) : (kj < ki);
        cnt += (before || (kj == ki && j < i)) ? 1.f : 0.f;
    }
    float r = blockReduceSum(cnt);
    if (threadIdx.x == 0) order[(int)r] = i;
}

// ---------------- scatter: rank-i candidate -> rank-i least-important slot ----
__global__ __launch_bounds__(256) void scatter_k(const int* __restrict__ cand_order,
                                                 const int* __restrict__ slot_order,
                                                 const float* __restrict__ sur,
                                                 int* __restrict__ row_src) {
    int i = blockIdx.x * 256 + threadIdx.x;   // i < BS_CAND
    int c = cand_order[i];
    if (sur[c] > THRESH) row_src[slot_order[i]] = c;
}

// ---------------- fp32 -> bf16 flat convert, 4 elems/thread ----------------
__global__ __launch_bounds__(256) void f2b_k(const float* __restrict__ in,
                                             __hip_bfloat16* __restrict__ out, int n4) {
    int i = blockIdx.x * 256 + threadIdx.x;
    if (i < n4) {
        float4 v = ((const float4*)in)[i];
        ushortx4 o;
        o.x = f2b_bits(v.x); o.y = f2b_bits(v.y);
        o.z = f2b_bits(v.z); o.w = f2b_bits(v.w);
        ((ushortx4*)out)[i] = o;
    }
}

// ---------------- build updated buffer (bf16), 4 elems/thread -------------
__global__ __launch_bounds__(256) void build_b_k(const float* __restrict__ mem,
                                                 const float* __restrict__ hid,
                                                 const int* __restrict__ src,
                                                 __hip_bfloat16* __restrict__ B) {
    int m = blockIdx.x;
    int s = src[m];
    const float4* r = (const float4*)((s < 0) ? (mem + (size_t)m * HDIM)
                                              : (hid + (size_t)s * HDIM));
    float4 v = r[threadIdx.x];                 // HDIM/4 == 256 == blockDim
    ushortx4 o;
    o.x = f2b_bits(v.x); o.y = f2b_bits(v.y);
    o.z = f2b_bits(v.z); o.w = f2b_bits(v.w);
    ((ushortx4*)(B + (size_t)m * HDIM))[threadIdx.x] = o;
}

// ---------------- bf16 transpose [R][C] -> [C][R] ----------------
__global__ __launch_bounds__(256) void transpose_k(const __hip_bfloat16* __restrict__ in,
                                                   __hip_bfloat16* __restrict__ out,
                                                   int R, int C) {
    __shared__ __hip_bfloat16 t[64][65];
    int cb = blockIdx.x * 64, rb = blockIdx.y * 64;
    int tx = threadIdx.x & 63, ty = threadIdx.x >> 6;
    #pragma unroll
    for (int k = 0; k < 16; k++) {
        int r = ty * 16 + k;
        t[r][tx] = in[(size_t)(rb + r) * C + cb + tx];
    }
    __syncthreads();
    #pragma unroll
    for (int k = 0; k < 16; k++) {
        int c = ty * 16 + k;
        out[(size_t)(cb + c) * R + rb + tx] = t[tx][c];
    }
}

// ---------------- async global->LDS helper ----------------
__device__ __forceinline__ void load_lds16(const __hip_bfloat16* g, __hip_bfloat16* l) {
    __builtin_amdgcn_global_load_lds(
        (const __attribute__((address_space(1))) void*)g,
        (__attribute__((address_space(3))) void*)l, 16, 0, 0);
}

// ---------------- BT-GEMM: C[M,N] = A[M,K] * Bt[N,K]^T  (m97 structure) ----------
// SWAP=1: bm from blockIdx.x, bn from blockIdx.y (XCD locality for A re-reads).
// EPI 0: outF[z*M*N + idx] = acc * scale       (fp32 out, split-K partial)
// EPI 1: outH[idx] = bf16(acc + bias[col])     (bf16 out)
// EPI 2: outH[idx] = bf16(exp(acc * scale))    (bf16 out, softmax numerator;
//         no max-subtraction needed: |S| <= ~3, exp safely in fp32 range)
template <int EPI, int SWAP>
__global__ __launch_bounds__(256) void gemm_bt(const __hip_bfloat16* __restrict__ A,
                                               const __hip_bfloat16* __restrict__ Bt,
                                               float* __restrict__ outF,
                                               __hip_bfloat16* __restrict__ outH,
                                               const float* __restrict__ bias,
                                               int M, int N, int K, int ksplit,
                                               float scale) {
    __shared__ alignas(16) __hip_bfloat16 Asm[128 * 64];
    __shared__ alignas(16) __hip_bfloat16 Bsm[128 * 64];
    const int tid = threadIdx.x;
    const int wave = tid >> 6, lane = tid & 63;
    const int bm = SWAP ? blockIdx.x : blockIdx.y;
    const int bn = SWAP ? blockIdx.y : blockIdx.x;
    const int kb = blockIdx.z * ksplit, ke = kb + ksplit;
    const int wr = (wave >> 1) * 64, wc = (wave & 1) * 64;
    const int lm = lane & 15, lq = lane >> 4;

    floatx4 acc[4][4];
    #pragma unroll
    for (int i = 0; i < 4; i++)
        #pragma unroll
        for (int j = 0; j < 4; j++) acc[i][j] = {0.f, 0.f, 0.f, 0.f};

    const __hip_bfloat16* Abase = A + (size_t)bm * 128 * K;
    const __hip_bfloat16* Bbase = Bt + (size_t)bn * 128 * K;

    for (int k0 = kb; k0 < ke; k0 += 64) {
        #pragma unroll
        for (int t = 0; t < 4; t++) {
            int c = (wave * 4 + t) * 64 + lane;       // 16B chunk index
            int row = c >> 3, col = (c & 7) * 8;
            load_lds16(Abase + (size_t)row * K + k0 + col, &Asm[(wave * 4 + t) * 512]);
        }
        #pragma unroll
        for (int t = 0; t < 4; t++) {
            int c = (wave * 4 + t) * 64 + lane;
            int row = c >> 3, col = (c & 7) * 8;
            load_lds16(Bbase + (size_t)row * K + k0 + col, &Bsm[(wave * 4 + t) * 512]);
        }
        __syncthreads();
        #pragma unroll
        for (int ks = 0; ks < 2; ks++) {
            shortx8 af[4], bfr[4];
            #pragma unroll
            for (int i = 0; i < 4; i++)
                af[i] = *(const shortx8*)(&Asm[(wr + i * 16 + lm) * 64 + ks * 32 + lq * 8]);
            #pragma unroll
            for (int j = 0; j < 4; j++)
                bfr[j] = *(const shortx8*)(&Bsm[(wc + j * 16 + lm) * 64 + ks * 32 + lq * 8]);
            #pragma unroll
            for (int i = 0; i < 4; i++)
                #pragma unroll
                for (int j = 0; j < 4; j++)
                    acc[i][j] = __builtin_amdgcn_mfma_f32_16x16x32_bf16(af[i], bfr[j],
                                                                        acc[i][j], 0, 0, 0);
        }
        __syncthreads();
    }

    float* outFz = outF + (size_t)blockIdx.z * M * N;
    #pragma unroll
    for (int i = 0; i < 4; i++) {
        int grow0 = bm * 128 + wr + i * 16 + lq * 4;
        #pragma unroll
        for (int j = 0; j < 4; j++) {
            int gcol = bn * 128 + wc + j * 16 + lm;
            #pragma unroll
            for (int r = 0; r < 4; r++) {
                float v = acc[i][j][r];
                size_t idx = (size_t)(grow0 + r) * N + gcol;
                if (EPI == 0)      outFz[idx] = v * scale;
                else if (EPI == 1) outH[idx] = __float2bfloat16(v + bias[gcol]);
                else               outH[idx] = __float2bfloat16(__expf(v * scale));
            }
        }
    }
}

// ---------------- row sums of E[4096][8192] bf16 -> fp32 ----------------
__global__ __launch_bounds__(256) void rowsumE_k(const __hip_bfloat16* __restrict__ E,
                                                 float* __restrict__ rowsum) {
    int row = blockIdx.x;
    const ushortx8* p = (const ushortx8*)(E + (size_t)row * MSLOTS);
    float s = 0.f;
    #pragma unroll
    for (int c = 0; c < 4; c++) {
        ushortx8 x = p[threadIdx.x + c * 256];
        #pragma unroll
        for (int e = 0; e < 8; e++) s += b2f_bits(x[e]);
    }
    float t = blockReduceSum(s);
    if (threadIdx.x == 0) rowsum[row] = t;
}

// ---------------- sum 4 fp32 partials, scale by 1/rowsum -> out ----------------
__global__ __launch_bounds__(256) void reduce4_k(const float4* __restrict__ p,
                                                 const float* __restrict__ rowsum,
                                                 float4* __restrict__ out, int n4) {
    int i = blockIdx.x * 256 + threadIdx.x;
    if (i < n4) {
        float inv = 1.f / rowsum[i >> 8];          // HDIM/4 = 256 float4 per row
        float4 a = p[i], b = p[i + n4], c = p[i + 2 * n4], d = p[i + 3 * n4];
        float4 o;
        o.x = ((a.x + b.x) + (c.x + d.x)) * inv;
        o.y = ((a.y + b.y) + (c.y + d.y)) * inv;
        o.z = ((a.z + b.z) + (c.z + d.z)) * inv;
        o.w = ((a.w + b.w) + (c.w + d.w)) * inv;
        out[i] = o;
    }
}

// ---------------- launch ----------------
extern "C" void kernel_launch(void* const* d_in, const int* in_sizes, int n_in,
                              void* d_out, int out_size, void* d_ws, size_t ws_size,
                              hipStream_t stream) {
    const float* hidden = (const float*)d_in[0];   // [2,2048,1024]
    const float* membuf = (const float*)d_in[1];   // [8192,1024]
    const float* imp    = (const float*)d_in[2];   // [8192]
    const float* Wq     = (const float*)d_in[3];   // [1024,1024]
    const float* bq     = (const float*)d_in[4];   // [1024]
    const float* Wk     = (const float*)d_in[5];   // [1024,1024]
    const float* bk     = (const float*)d_in[6];   // [1024]
    const float* noise  = (const float*)d_in[7];   // [8192]

    char* ws = (char*)d_ws;
    size_t off = 0;
    auto alloc = [&](size_t bytes) -> void* {
        void* p = ws + off;
        off += (bytes + 255) & ~(size_t)255;
        return p;
    };
    // --- persistent region (front) ---
    float*          surprise = (float*)alloc(BS_CAND * 4);
    float*          skeys    = (float*)alloc(MSLOTS * 4);
    float*          rowsum   = (float*)alloc(BS_CAND * 4);
    int*            cand_ord = (int*)alloc(BS_CAND * 4);
    int*            slot_ord = (int*)alloc(MSLOTS * 4);
    int*            row_src  = (int*)alloc(MSLOTS * 4);
    __hip_bfloat16* Wqbf = (__hip_bfloat16*)alloc((size_t)HDIM * HDIM * 2);    // 2 MB
    __hip_bfloat16* Wkbf = (__hip_bfloat16*)alloc((size_t)HDIM * HDIM * 2);    // 2 MB
    __hip_bfloat16* BbfT = (__hip_bfloat16*)alloc((size_t)HDIM * MSLOTS * 2);  // 16 MB
    // --- Sbf region (64 MB), overlaid with Hbf (8 MB) + Bbf (16 MB) which die
    // before the scores GEMM writes Sbf ---
    size_t s_base = off;
    __hip_bfloat16* Sbf = (__hip_bfloat16*)(ws + s_base);                      // 64 MB
    __hip_bfloat16* Hbf = (__hip_bfloat16*)(ws + s_base);                      //  8 MB
    __hip_bfloat16* Bbf = (__hip_bfloat16*)(ws + s_base + (size_t)BS_CAND * HDIM * 2);
    off = s_base + ((size_t)BS_CAND * MSLOTS * 2 + 255) & ~(size_t)255;
    // --- tail region: qbf+mkbf live until scores GEMM; PV partials (64 MB)
    // overlay them afterwards ---
    size_t t_base = off;
    __hip_bfloat16* qbf  = (__hip_bfloat16*)alloc((size_t)BS_CAND * HDIM * 2); // 8 MB
    __hip_bfloat16* mkbf = (__hip_bfloat16*)alloc((size_t)MSLOTS * HDIM * 2);  // 16 MB
    float*          part = (float*)(ws + t_base);       // 4 x 16 MB fp32 partials
    // peak usage = t_base + 64 MB  (~148 MB total)

    // 1) selection phase
    surprise_k<<<BS_CAND, 256, 0, stream>>>(hidden, surprise);
    slot_keys_k<<<MSLOTS / 256, 256, 0, stream>>>(imp, noise, skeys, row_src);
    rank_k<1><<<BS_CAND, 256, 0, stream>>>(surprise, BS_CAND, cand_ord);
    rank_k<0><<<MSLOTS, 256, 0, stream>>>(skeys, MSLOTS, slot_ord);
    scatter_k<<<BS_CAND / 256, 256, 0, stream>>>(cand_ord, slot_ord, surprise, row_src);

    // 2) bf16 materialization
    f2b_k<<<(BS_CAND * HDIM / 4) / 256, 256, 0, stream>>>(hidden, Hbf, BS_CAND * HDIM / 4);
    f2b_k<<<(HDIM * HDIM / 4) / 256, 256, 0, stream>>>(Wq, Wqbf, HDIM * HDIM / 4);
    f2b_k<<<(HDIM * HDIM / 4) / 256, 256, 0, stream>>>(Wk, Wkbf, HDIM * HDIM / 4);
    build_b_k<<<MSLOTS, 256, 0, stream>>>(membuf, hidden, row_src, Bbf);
    transpose_k<<<dim3(HDIM / 64, MSLOTS / 64), 256, 0, stream>>>(Bbf, BbfT, MSLOTS, HDIM);

    // 3) q = hidden @ Wq^T + bq   -> bf16 [4096,1024]   (Hbf dies after this)
    gemm_bt<1, 0><<<dim3(HDIM / 128, BS_CAND / 128), 256, 0, stream>>>(
        Hbf, Wqbf, nullptr, qbf, bq, BS_CAND, HDIM, HDIM, HDIM, 1.f);
    // 4) mk = newbuf @ Wk^T + bk  -> bf16 [8192,1024]   (Bbf dies after this)
    gemm_bt<1, 0><<<dim3(HDIM / 128, MSLOTS / 128), 256, 0, stream>>>(
        Bbf, Wkbf, nullptr, mkbf, bk, MSLOTS, HDIM, HDIM, HDIM, 1.f);
    // 5) E = bf16(exp((q @ mk^T)/32))  [4096,8192] — plain stores, no atomics
    gemm_bt<2, 0><<<dim3(MSLOTS / 128, BS_CAND / 128), 256, 0, stream>>>(
        qbf, mkbf, nullptr, Sbf, nullptr, BS_CAND, MSLOTS, HDIM, HDIM, 0.03125f);
    // 6) rowsum = row sums of E    -> fp32 [4096]
    rowsumE_k<<<BS_CAND, 256, 0, stream>>>(Sbf, rowsum);
    // 7) split-K PV: partial[z] = E @ newbuf over K-chunk z  (overlays qbf/mkbf)
    //    SWAP=1: bm on grid.x so all bn-blocks of one bm share an XCD (L2 reuse)
    gemm_bt<0, 1><<<dim3(BS_CAND / 128, HDIM / 128, PV_SPLIT), 256, 0, stream>>>(
        Sbf, BbfT, part, nullptr, nullptr, BS_CAND, HDIM, MSLOTS,
        MSLOTS / PV_SPLIT, 1.f);
    // 8) out = (sum of 4 partials) / rowsum   -> fp32 [4096,1024]
    reduce4_k<<<(BS_CAND * HDIM / 4) / 256, 256, 0, stream>>>(
        (const float4*)part, rowsum, (float4*)d_out, BS_CAND * HDIM / 4);
}

// Round 7
// 398.200 us; speedup vs baseline: 1.1621x; 1.1054x over previous
//
#include <hip/hip_runtime.h>
#include <hip/hip_bf16.h>
#include <math.h>
#include <stdint.h>

typedef __attribute__((ext_vector_type(4))) float floatx4;
typedef __attribute__((ext_vector_type(8))) short shortx8;
typedef __attribute__((ext_vector_type(8))) unsigned short ushortx8;
typedef __attribute__((ext_vector_type(4))) unsigned short ushortx4;

#define BS_CAND 4096   // B*S
#define HDIM    1024
#define MSLOTS  8192
#define THRESH  64.0f
#define PV_SPLIT 4

__device__ __forceinline__ unsigned short f2b_bits(float f) {
    __hip_bfloat16 b = __float2bfloat16(f);
    return *(unsigned short*)&b;
}
__device__ __forceinline__ float b2f_bits(unsigned short u) {
    return __uint_as_float(((unsigned)u) << 16);
}

// ---------------- reduction helpers (blockDim == 256) ----------------
__device__ __forceinline__ float blockReduceSum(float x) {
    __shared__ float red[4];
    #pragma unroll
    for (int o = 32; o > 0; o >>= 1) x += __shfl_down(x, o, 64);
    int lane = threadIdx.x & 63, w = threadIdx.x >> 6;
    if (lane == 0) red[w] = x;
    __syncthreads();
    float s = red[0] + red[1] + red[2] + red[3];
    __syncthreads();
    return s;
}

// ---------------- surprise = 2*||row||_2 ----------------
__global__ __launch_bounds__(256) void surprise_k(const float* __restrict__ h,
                                                  float* __restrict__ sur) {
    int row = blockIdx.x;
    const float* p = h + (size_t)row * HDIM;
    float s = 0.f;
    for (int i = threadIdx.x; i < HDIM; i += 256) { float v = p[i]; s += v * v; }
    float tot = blockReduceSum(s);
    if (threadIdx.x == 0) sur[row] = 2.0f * sqrtf(tot);
}

// ---------------- slot keys = imp + 1e-6*noise; row_src = -1 ----------------
__global__ __launch_bounds__(256) void slot_keys_k(const float* __restrict__ imp,
                                                   const float* __restrict__ noi,
                                                   float* __restrict__ keys,
                                                   int* __restrict__ row_src) {
    int i = blockIdx.x * 256 + threadIdx.x;
    keys[i] = imp[i] + noi[i] * 1e-6f;
    row_src[i] = -1;
}

// ---------------- rank by counting: one BLOCK per element ----------------
// DESC=1: rank among descending order; DESC=0: ascending. Stable (ties by index).
template <int DESC>
__global__ __launch_bounds__(256) void rank_k(const float* __restrict__ keys,
                                              int n, int* __restrict__ order) {
    int i = blockIdx.x;
    float ki = keys[i];
    float cnt = 0.f;
    for (int j = threadIdx.x; j < n; j += 256) {
        float kj = keys[j];
        bool before = DESC ? (kj > ki) : (kj < ki);
        cnt += (before || (kj == ki && j < i)) ? 1.f : 0.f;
    }
    float r = blockReduceSum(cnt);
    if (threadIdx.x == 0) order[(int)r] = i;
}

// ---------------- scatter: rank-i candidate -> rank-i least-important slot ----
__global__ __launch_bounds__(256) void scatter_k(const int* __restrict__ cand_order,
                                                 const int* __restrict__ slot_order,
                                                 const float* __restrict__ sur,
                                                 int* __restrict__ row_src) {
    int i = blockIdx.x * 256 + threadIdx.x;   // i < BS_CAND
    int c = cand_order[i];
    if (sur[c] > THRESH) row_src[slot_order[i]] = c;
}

// ---------------- fp32 -> bf16 flat convert, 4 elems/thread ----------------
__global__ __launch_bounds__(256) void f2b_k(const float* __restrict__ in,
                                             __hip_bfloat16* __restrict__ out, int n4) {
    int i = blockIdx.x * 256 + threadIdx.x;
    if (i < n4) {
        float4 v = ((const float4*)in)[i];
        ushortx4 o;
        o.x = f2b_bits(v.x); o.y = f2b_bits(v.y);
        o.z = f2b_bits(v.z); o.w = f2b_bits(v.w);
        ((ushortx4*)out)[i] = o;
    }
}

// ---------------- build updated buffer (bf16), 4 elems/thread -------------
__global__ __launch_bounds__(256) void build_b_k(const float* __restrict__ mem,
                                                 const float* __restrict__ hid,
                                                 const int* __restrict__ src,
                                                 __hip_bfloat16* __restrict__ B) {
    int m = blockIdx.x;
    int s = src[m];
    const float4* r = (const float4*)((s < 0) ? (mem + (size_t)m * HDIM)
                                              : (hid + (size_t)s * HDIM));
    float4 v = r[threadIdx.x];                 // HDIM/4 == 256 == blockDim
    ushortx4 o;
    o.x = f2b_bits(v.x); o.y = f2b_bits(v.y);
    o.z = f2b_bits(v.z); o.w = f2b_bits(v.w);
    ((ushortx4*)(B + (size_t)m * HDIM))[threadIdx.x] = o;
}

// ---------------- bf16 transpose [R][C] -> [C][R] ----------------
__global__ __launch_bounds__(256) void transpose_k(const __hip_bfloat16* __restrict__ in,
                                                   __hip_bfloat16* __restrict__ out,
                                                   int R, int C) {
    __shared__ __hip_bfloat16 t[64][65];
    int cb = blockIdx.x * 64, rb = blockIdx.y * 64;
    int tx = threadIdx.x & 63, ty = threadIdx.x >> 6;
    #pragma unroll
    for (int k = 0; k < 16; k++) {
        int r = ty * 16 + k;
        t[r][tx] = in[(size_t)(rb + r) * C + cb + tx];
    }
    __syncthreads();
    #pragma unroll
    for (int k = 0; k < 16; k++) {
        int c = ty * 16 + k;
        out[(size_t)(cb + c) * R + rb + tx] = t[tx][c];
    }
}

// ---------------- async global->LDS helper ----------------
__device__ __forceinline__ void load_lds16(const __hip_bfloat16* g, __hip_bfloat16* l) {
    __builtin_amdgcn_global_load_lds(
        (const __attribute__((address_space(1))) void*)g,
        (__attribute__((address_space(3))) void*)l, 16, 0, 0);
}

// ---------------- BT-GEMM: C[M,N] = A[M,K] * Bt[N,K]^T ----------
// LDS tiles split into two 128x32 planes (row = 64 B = 16 banks' words) so the
// ds_read_b128 fragment reads hit all 32 banks uniformly (depth 8, conflict-free).
// With the old 128x64 layout (row = 128 B = 32 words), bank index was independent
// of the row -> 16 lanes on the same 4 banks = 2x LDS slowdown (SQ_LDS_BANK_CONFLICT 2.5e7).
// SWAP=1: bm from blockIdx.x, bn from blockIdx.y (XCD locality for A re-reads).
// EPI 0: outF[z*M*N + idx] = acc * scale       (fp32 out, split-K partial)
// EPI 1: outH[idx] = bf16(acc + bias[col])     (bf16 out)
// EPI 2: outH[idx] = bf16(exp(acc * scale))    (bf16 out, softmax numerator;
//         no max-subtraction needed: |S| <= ~3, exp safely in fp32 range)
template <int EPI, int SWAP>
__global__ __launch_bounds__(256) void gemm_bt(const __hip_bfloat16* __restrict__ A,
                                               const __hip_bfloat16* __restrict__ Bt,
                                               float* __restrict__ outF,
                                               __hip_bfloat16* __restrict__ outH,
                                               const float* __restrict__ bias,
                                               int M, int N, int K, int ksplit,
                                               float scale) {
    __shared__ alignas(16) __hip_bfloat16 Asm[2][128 * 32];   // plane p holds k-sub [p*32, p*32+32)
    __shared__ alignas(16) __hip_bfloat16 Bsm[2][128 * 32];
    const int tid = threadIdx.x;
    const int wave = tid >> 6, lane = tid & 63;
    const int bm = SWAP ? blockIdx.x : blockIdx.y;
    const int bn = SWAP ? blockIdx.y : blockIdx.x;
    const int kb = blockIdx.z * ksplit, ke = kb + ksplit;
    const int wr = (wave >> 1) * 64, wc = (wave & 1) * 64;
    const int lm = lane & 15, lq = lane >> 4;

    floatx4 acc[4][4];
    #pragma unroll
    for (int i = 0; i < 4; i++)
        #pragma unroll
        for (int j = 0; j < 4; j++) acc[i][j] = {0.f, 0.f, 0.f, 0.f};

    const __hip_bfloat16* Abase = A + (size_t)bm * 128 * K;
    const __hip_bfloat16* Bbase = Bt + (size_t)bn * 128 * K;

    for (int k0 = kb; k0 < ke; k0 += 64) {
        #pragma unroll
        for (int t = 0; t < 4; t++) {
            int g = wave * 4 + t;              // call id 0..15
            int p = g >> 3;                    // plane
            int pcb = (g & 7) << 6;            // plane-chunk base (64 chunks/call)
            int pc = pcb + lane;               // plane chunk 0..511
            int row = pc >> 2, cc = pc & 3;    // 4 x 16B chunks per 64B plane row
            load_lds16(Abase + (size_t)row * K + k0 + p * 32 + cc * 8,
                       &Asm[p][pcb * 8]);
        }
        #pragma unroll
        for (int t = 0; t < 4; t++) {
            int g = wave * 4 + t;
            int p = g >> 3;
            int pcb = (g & 7) << 6;
            int pc = pcb + lane;
            int row = pc >> 2, cc = pc & 3;
            load_lds16(Bbase + (size_t)row * K + k0 + p * 32 + cc * 8,
                       &Bsm[p][pcb * 8]);
        }
        __syncthreads();
        #pragma unroll
        for (int ks = 0; ks < 2; ks++) {
            shortx8 af[4], bfr[4];
            #pragma unroll
            for (int i = 0; i < 4; i++)
                af[i] = *(const shortx8*)(&Asm[ks][(wr + i * 16 + lm) * 32 + lq * 8]);
            #pragma unroll
            for (int j = 0; j < 4; j++)
                bfr[j] = *(const shortx8*)(&Bsm[ks][(wc + j * 16 + lm) * 32 + lq * 8]);
            #pragma unroll
            for (int i = 0; i < 4; i++)
                #pragma unroll
                for (int j = 0; j < 4; j++)
                    acc[i][j] = __builtin_amdgcn_mfma_f32_16x16x32_bf16(af[i], bfr[j],
                                                                        acc[i][j], 0, 0, 0);
        }
        __syncthreads();
    }

    float* outFz = outF + (size_t)blockIdx.z * M * N;
    #pragma unroll
    for (int i = 0; i < 4; i++) {
        int grow0 = bm * 128 + wr + i * 16 + lq * 4;
        #pragma unroll
        for (int j = 0; j < 4; j++) {
            int gcol = bn * 128 + wc + j * 16 + lm;
            #pragma unroll
            for (int r = 0; r < 4; r++) {
                float v = acc[i][j][r];
                size_t idx = (size_t)(grow0 + r) * N + gcol;
                if (EPI == 0)      outFz[idx] = v * scale;
                else if (EPI == 1) outH[idx] = __float2bfloat16(v + bias[gcol]);
                else               outH[idx] = __float2bfloat16(__expf(v * scale));
            }
        }
    }
}

// ---------------- row sums of E[4096][8192] bf16 -> fp32 ----------------
__global__ __launch_bounds__(256) void rowsumE_k(const __hip_bfloat16* __restrict__ E,
                                                 float* __restrict__ rowsum) {
    int row = blockIdx.x;
    const ushortx8* p = (const ushortx8*)(E + (size_t)row * MSLOTS);
    float s = 0.f;
    #pragma unroll
    for (int c = 0; c < 4; c++) {
        ushortx8 x = p[threadIdx.x + c * 256];
        #pragma unroll
        for (int e = 0; e < 8; e++) s += b2f_bits(x[e]);
    }
    float t = blockReduceSum(s);
    if (threadIdx.x == 0) rowsum[row] = t;
}

// ---------------- sum 4 fp32 partials, scale by 1/rowsum -> out ----------------
__global__ __launch_bounds__(256) void reduce4_k(const float4* __restrict__ p,
                                                 const float* __restrict__ rowsum,
                                                 float4* __restrict__ out, int n4) {
    int i = blockIdx.x * 256 + threadIdx.x;
    if (i < n4) {
        float inv = 1.f / rowsum[i >> 8];          // HDIM/4 = 256 float4 per row
        float4 a = p[i], b = p[i + n4], c = p[i + 2 * n4], d = p[i + 3 * n4];
        float4 o;
        o.x = ((a.x + b.x) + (c.x + d.x)) * inv;
        o.y = ((a.y + b.y) + (c.y + d.y)) * inv;
        o.z = ((a.z + b.z) + (c.z + d.z)) * inv;
        o.w = ((a.w + b.w) + (c.w + d.w)) * inv;
        out[i] = o;
    }
}

// ---------------- launch ----------------
extern "C" void kernel_launch(void* const* d_in, const int* in_sizes, int n_in,
                              void* d_out, int out_size, void* d_ws, size_t ws_size,
                              hipStream_t stream) {
    const float* hidden = (const float*)d_in[0];   // [2,2048,1024]
    const float* membuf = (const float*)d_in[1];   // [8192,1024]
    const float* imp    = (const float*)d_in[2];   // [8192]
    const float* Wq     = (const float*)d_in[3];   // [1024,1024]
    const float* bq     = (const float*)d_in[4];   // [1024]
    const float* Wk     = (const float*)d_in[5];   // [1024,1024]
    const float* bk     = (const float*)d_in[6];   // [1024]
    const float* noise  = (const float*)d_in[7];   // [8192]

    char* ws = (char*)d_ws;
    size_t off = 0;
    auto alloc = [&](size_t bytes) -> void* {
        void* p = ws + off;
        off += (bytes + 255) & ~(size_t)255;
        return p;
    };
    // --- persistent region (front) ---
    float*          surprise = (float*)alloc(BS_CAND * 4);
    float*          skeys    = (float*)alloc(MSLOTS * 4);
    float*          rowsum   = (float*)alloc(BS_CAND * 4);
    int*            cand_ord = (int*)alloc(BS_CAND * 4);
    int*            slot_ord = (int*)alloc(MSLOTS * 4);
    int*            row_src  = (int*)alloc(MSLOTS * 4);
    __hip_bfloat16* Wqbf = (__hip_bfloat16*)alloc((size_t)HDIM * HDIM * 2);    // 2 MB
    __hip_bfloat16* Wkbf = (__hip_bfloat16*)alloc((size_t)HDIM * HDIM * 2);    // 2 MB
    __hip_bfloat16* BbfT = (__hip_bfloat16*)alloc((size_t)HDIM * MSLOTS * 2);  // 16 MB
    // --- Sbf region (64 MB), overlaid with Hbf (8 MB) + Bbf (16 MB) which die
    // before the scores GEMM writes Sbf ---
    size_t s_base = off;
    __hip_bfloat16* Sbf = (__hip_bfloat16*)(ws + s_base);                      // 64 MB
    __hip_bfloat16* Hbf = (__hip_bfloat16*)(ws + s_base);                      //  8 MB
    __hip_bfloat16* Bbf = (__hip_bfloat16*)(ws + s_base + (size_t)BS_CAND * HDIM * 2);
    off = s_base + ((size_t)BS_CAND * MSLOTS * 2 + 255) & ~(size_t)255;
    // --- tail region: qbf+mkbf live until scores GEMM; PV partials (64 MB)
    // overlay them afterwards ---
    size_t t_base = off;
    __hip_bfloat16* qbf  = (__hip_bfloat16*)alloc((size_t)BS_CAND * HDIM * 2); // 8 MB
    __hip_bfloat16* mkbf = (__hip_bfloat16*)alloc((size_t)MSLOTS * HDIM * 2);  // 16 MB
    float*          part = (float*)(ws + t_base);       // 4 x 16 MB fp32 partials
    // peak usage = t_base + 64 MB  (~148 MB total)

    // 1) selection phase
    surprise_k<<<BS_CAND, 256, 0, stream>>>(hidden, surprise);
    slot_keys_k<<<MSLOTS / 256, 256, 0, stream>>>(imp, noise, skeys, row_src);
    rank_k<1><<<BS_CAND, 256, 0, stream>>>(surprise, BS_CAND, cand_ord);
    rank_k<0><<<MSLOTS, 256, 0, stream>>>(skeys, MSLOTS, slot_ord);
    scatter_k<<<BS_CAND / 256, 256, 0, stream>>>(cand_ord, slot_ord, surprise, row_src);

    // 2) bf16 materialization
    f2b_k<<<(BS_CAND * HDIM / 4) / 256, 256, 0, stream>>>(hidden, Hbf, BS_CAND * HDIM / 4);
    f2b_k<<<(HDIM * HDIM / 4) / 256, 256, 0, stream>>>(Wq, Wqbf, HDIM * HDIM / 4);
    f2b_k<<<(HDIM * HDIM / 4) / 256, 256, 0, stream>>>(Wk, Wkbf, HDIM * HDIM / 4);
    build_b_k<<<MSLOTS, 256, 0, stream>>>(membuf, hidden, row_src, Bbf);
    transpose_k<<<dim3(HDIM / 64, MSLOTS / 64), 256, 0, stream>>>(Bbf, BbfT, MSLOTS, HDIM);

    // 3) q = hidden @ Wq^T + bq   -> bf16 [4096,1024]   (Hbf dies after this)
    gemm_bt<1, 0><<<dim3(HDIM / 128, BS_CAND / 128), 256, 0, stream>>>(
        Hbf, Wqbf, nullptr, qbf, bq, BS_CAND, HDIM, HDIM, HDIM, 1.f);
    // 4) mk = newbuf @ Wk^T + bk  -> bf16 [8192,1024]   (Bbf dies after this)
    gemm_bt<1, 0><<<dim3(HDIM / 128, MSLOTS / 128), 256, 0, stream>>>(
        Bbf, Wkbf, nullptr, mkbf, bk, MSLOTS, HDIM, HDIM, HDIM, 1.f);
    // 5) E = bf16(exp((q @ mk^T)/32))  [4096,8192] — plain stores, no atomics
    gemm_bt<2, 0><<<dim3(MSLOTS / 128, BS_CAND / 128), 256, 0, stream>>>(
        qbf, mkbf, nullptr, Sbf, nullptr, BS_CAND, MSLOTS, HDIM, HDIM, 0.03125f);
    // 6) rowsum = row sums of E    -> fp32 [4096]
    rowsumE_k<<<BS_CAND, 256, 0, stream>>>(Sbf, rowsum);
    // 7) split-K PV: partial[z] = E @ newbuf over K-chunk z  (overlays qbf/mkbf)
    //    SWAP=1: bm on grid.x so all bn-blocks of one bm share an XCD (L2 reuse)
    gemm_bt<0, 1><<<dim3(BS_CAND / 128, HDIM / 128, PV_SPLIT), 256, 0, stream>>>(
        Sbf, BbfT, part, nullptr, nullptr, BS_CAND, HDIM, MSLOTS,
        MSLOTS / PV_SPLIT, 1.f);
    // 8) out = (sum of 4 partials) / rowsum   -> fp32 [4096,1024]
    reduce4_k<<<(BS_CAND * HDIM / 4) / 256, 256, 0, stream>>>(
        (const float4*)part, rowsum, (float4*)d_out, BS_CAND * HDIM / 4);
}

// Round 8
// 382.212 us; speedup vs baseline: 1.2108x; 1.0418x over previous
//
#include <hip/hip_runtime.h>
#include <hip/hip_bf16.h>
#include <math.h>
#include <stdint.h>

typedef __attribute__((ext_vector_type(4))) float floatx4;
typedef __attribute__((ext_vector_type(8))) short shortx8;
typedef __attribute__((ext_vector_type(8))) unsigned short ushortx8;
typedef __attribute__((ext_vector_type(4))) unsigned short ushortx4;

#define BS_CAND 4096   // B*S
#define HDIM    1024
#define MSLOTS  8192
#define THRESH  64.0f
#define PV_SPLIT 4

__device__ __forceinline__ unsigned short f2b_bits(float f) {
    __hip_bfloat16 b = __float2bfloat16(f);
    return *(unsigned short*)&b;
}
__device__ __forceinline__ float b2f_bits(unsigned short u) {
    return __uint_as_float(((unsigned)u) << 16);
}

// ---------------- reduction helpers (blockDim == 256) ----------------
__device__ __forceinline__ float blockReduceSum(float x) {
    __shared__ float red[4];
    #pragma unroll
    for (int o = 32; o > 0; o >>= 1) x += __shfl_down(x, o, 64);
    int lane = threadIdx.x & 63, w = threadIdx.x >> 6;
    if (lane == 0) red[w] = x;
    __syncthreads();
    float s = red[0] + red[1] + red[2] + red[3];
    __syncthreads();
    return s;
}

// ------- fused: surprise = 2*||row|| AND bf16 cast of hidden ----------------
__global__ __launch_bounds__(256) void norm_f2b_k(const float* __restrict__ h,
                                                  float* __restrict__ sur,
                                                  __hip_bfloat16* __restrict__ out) {
    int row = blockIdx.x;
    float4 v = ((const float4*)(h + (size_t)row * HDIM))[threadIdx.x];
    ushortx4 o;
    o.x = f2b_bits(v.x); o.y = f2b_bits(v.y);
    o.z = f2b_bits(v.z); o.w = f2b_bits(v.w);
    ((ushortx4*)(out + (size_t)row * HDIM))[threadIdx.x] = o;
    float s = v.x * v.x + v.y * v.y + v.z * v.z + v.w * v.w;
    float tot = blockReduceSum(s);
    if (threadIdx.x == 0) sur[row] = 2.0f * sqrtf(tot);
}

// ---------------- slot keys = imp + 1e-6*noise; row_src = -1 ----------------
__global__ __launch_bounds__(256) void slot_keys_k(const float* __restrict__ imp,
                                                   const float* __restrict__ noi,
                                                   float* __restrict__ keys,
                                                   int* __restrict__ row_src) {
    int i = blockIdx.x * 256 + threadIdx.x;
    keys[i] = imp[i] + noi[i] * 1e-6f;
    row_src[i] = -1;
}

// ---------------- rank by counting: one BLOCK per element ----------------
// DESC=1: rank among descending order; DESC=0: ascending. Stable (ties by index).
template <int DESC>
__global__ __launch_bounds__(256) void rank_k(const float* __restrict__ keys,
                                              int n, int* __restrict__ order) {
    int i = blockIdx.x;
    float ki = keys[i];
    float cnt = 0.f;
    for (int j = threadIdx.x; j < n; j += 256) {
        float kj = keys[j];
        bool before = DESC ? (kj > ki) : (kj < ki);
        cnt += (before || (kj == ki && j < i)) ? 1.f : 0.f;
    }
    float r = blockReduceSum(cnt);
    if (threadIdx.x == 0) order[(int)r] = i;
}

// ---------------- scatter: rank-i candidate -> rank-i least-important slot ----
__global__ __launch_bounds__(256) void scatter_k(const int* __restrict__ cand_order,
                                                 const int* __restrict__ slot_order,
                                                 const float* __restrict__ sur,
                                                 int* __restrict__ row_src) {
    int i = blockIdx.x * 256 + threadIdx.x;   // i < BS_CAND
    int c = cand_order[i];
    if (sur[c] > THRESH) row_src[slot_order[i]] = c;
}

// ---------------- fp32 -> bf16 for Wq and Wk in one launch ----------------
__global__ __launch_bounds__(256) void f2b2_k(const float* __restrict__ inA,
                                              __hip_bfloat16* __restrict__ outA,
                                              const float* __restrict__ inB,
                                              __hip_bfloat16* __restrict__ outB,
                                              int n4) {
    int i = blockIdx.x * 256 + threadIdx.x;
    const float* in = (i < n4) ? inA : inB;
    __hip_bfloat16* out = (i < n4) ? outA : outB;
    int j = (i < n4) ? i : (i - n4);
    float4 v = ((const float4*)in)[j];
    ushortx4 o;
    o.x = f2b_bits(v.x); o.y = f2b_bits(v.y);
    o.z = f2b_bits(v.z); o.w = f2b_bits(v.w);
    ((ushortx4*)out)[j] = o;
}

// ---------------- build updated buffer (bf16), 4 elems/thread -------------
__global__ __launch_bounds__(256) void build_b_k(const float* __restrict__ mem,
                                                 const float* __restrict__ hid,
                                                 const int* __restrict__ src,
                                                 __hip_bfloat16* __restrict__ B) {
    int m = blockIdx.x;
    int s = src[m];
    const float4* r = (const float4*)((s < 0) ? (mem + (size_t)m * HDIM)
                                              : (hid + (size_t)s * HDIM));
    float4 v = r[threadIdx.x];                 // HDIM/4 == 256 == blockDim
    ushortx4 o;
    o.x = f2b_bits(v.x); o.y = f2b_bits(v.y);
    o.z = f2b_bits(v.z); o.w = f2b_bits(v.w);
    ((ushortx4*)(B + (size_t)m * HDIM))[threadIdx.x] = o;
}

// ---------------- bf16 transpose [R][C] -> [C][R] ----------------
__global__ __launch_bounds__(256) void transpose_k(const __hip_bfloat16* __restrict__ in,
                                                   __hip_bfloat16* __restrict__ out,
                                                   int R, int C) {
    __shared__ __hip_bfloat16 t[64][65];
    int cb = blockIdx.x * 64, rb = blockIdx.y * 64;
    int tx = threadIdx.x & 63, ty = threadIdx.x >> 6;
    #pragma unroll
    for (int k = 0; k < 16; k++) {
        int r = ty * 16 + k;
        t[r][tx] = in[(size_t)(rb + r) * C + cb + tx];
    }
    __syncthreads();
    #pragma unroll
    for (int k = 0; k < 16; k++) {
        int c = ty * 16 + k;
        out[(size_t)(cb + c) * R + rb + tx] = t[tx][c];
    }
}

// ---------------- async global->LDS helper ----------------
__device__ __forceinline__ void load_lds16(const __hip_bfloat16* g, __hip_bfloat16* l) {
    __builtin_amdgcn_global_load_lds(
        (const __attribute__((address_space(1))) void*)g,
        (__attribute__((address_space(3))) void*)l, 16, 0, 0);
}

// ---------------- BT-GEMM: C[M,N] = A[M,K] * Bt[N,K]^T ----------
// LDS tiles as two 128x32 planes (row = 64 B = 16 bank-words) so ds_read_b128
// fragment reads hit all 32 banks uniformly (conflict-free beyond the inherent
// depth-8 of b128). SWAP=1: bm on blockIdx.x (XCD locality for A re-reads).
// EPI 0: outF[z*M*N + idx] = acc * scale       (fp32 out, split-K partial)
// EPI 1: outH[idx] = bf16(acc + biasSel[col]); Bt/bias switch at block-row rows0b
//        (fused q/mk projection: A = [H; B] contiguous, out = [q; mk] contiguous)
// EPI 2: outH[idx] = bf16(exp(acc * scale))    (softmax numerator; |S|<=~3 so
//        max-subtraction is unnecessary — exp safely in fp32 range)
template <int EPI, int SWAP>
__global__ __launch_bounds__(256) void gemm_bt(const __hip_bfloat16* __restrict__ A,
                                               const __hip_bfloat16* __restrict__ Bt,
                                               const __hip_bfloat16* __restrict__ Bt2,
                                               float* __restrict__ outF,
                                               __hip_bfloat16* __restrict__ outH,
                                               const float* __restrict__ bias,
                                               const float* __restrict__ bias2,
                                               int rows0b,
                                               int M, int N, int K, int ksplit,
                                               float scale) {
    __shared__ alignas(16) __hip_bfloat16 Asm[2][128 * 32];   // plane p: k-sub [p*32,p*32+32)
    __shared__ alignas(16) __hip_bfloat16 Bsm[2][128 * 32];
    const int tid = threadIdx.x;
    const int wave = tid >> 6, lane = tid & 63;
    const int bm = SWAP ? blockIdx.x : blockIdx.y;
    const int bn = SWAP ? blockIdx.y : blockIdx.x;
    const int kb = blockIdx.z * ksplit, ke = kb + ksplit;
    const int wr = (wave >> 1) * 64, wc = (wave & 1) * 64;
    const int lm = lane & 15, lq = lane >> 4;

    const __hip_bfloat16* BtSel = (EPI == 1 && bm >= rows0b) ? Bt2 : Bt;
    const float* biasSel = (EPI == 1 && bm >= rows0b) ? bias2 : bias;

    floatx4 acc[4][4];
    #pragma unroll
    for (int i = 0; i < 4; i++)
        #pragma unroll
        for (int j = 0; j < 4; j++) acc[i][j] = {0.f, 0.f, 0.f, 0.f};

    const __hip_bfloat16* Abase = A + (size_t)bm * 128 * K;
    const __hip_bfloat16* Bbase = BtSel + (size_t)bn * 128 * K;

    for (int k0 = kb; k0 < ke; k0 += 64) {
        #pragma unroll
        for (int t = 0; t < 4; t++) {
            int g = wave * 4 + t;              // call id 0..15
            int p = g >> 3;                    // plane
            int pcb = (g & 7) << 6;            // plane-chunk base
            int pc = pcb + lane;               // plane chunk 0..511
            int row = pc >> 2, cc = pc & 3;    // 4 x 16B chunks per 64B plane row
            load_lds16(Abase + (size_t)row * K + k0 + p * 32 + cc * 8,
                       &Asm[p][pcb * 8]);
        }
        #pragma unroll
        for (int t = 0; t < 4; t++) {
            int g = wave * 4 + t;
            int p = g >> 3;
            int pcb = (g & 7) << 6;
            int pc = pcb + lane;
            int row = pc >> 2, cc = pc & 3;
            load_lds16(Bbase + (size_t)row * K + k0 + p * 32 + cc * 8,
                       &Bsm[p][pcb * 8]);
        }
        __syncthreads();
        #pragma unroll
        for (int ks = 0; ks < 2; ks++) {
            shortx8 af[4], bfr[4];
            #pragma unroll
            for (int i = 0; i < 4; i++)
                af[i] = *(const shortx8*)(&Asm[ks][(wr + i * 16 + lm) * 32 + lq * 8]);
            #pragma unroll
            for (int j = 0; j < 4; j++)
                bfr[j] = *(const shortx8*)(&Bsm[ks][(wc + j * 16 + lm) * 32 + lq * 8]);
            #pragma unroll
            for (int i = 0; i < 4; i++)
                #pragma unroll
                for (int j = 0; j < 4; j++)
                    acc[i][j] = __builtin_amdgcn_mfma_f32_16x16x32_bf16(af[i], bfr[j],
                                                                        acc[i][j], 0, 0, 0);
        }
        __syncthreads();
    }

    float* outFz = outF + (size_t)blockIdx.z * M * N;
    #pragma unroll
    for (int i = 0; i < 4; i++) {
        int grow0 = bm * 128 + wr + i * 16 + lq * 4;
        #pragma unroll
        for (int j = 0; j < 4; j++) {
            int gcol = bn * 128 + wc + j * 16 + lm;
            #pragma unroll
            for (int r = 0; r < 4; r++) {
                float v = acc[i][j][r];
                size_t idx = (size_t)(grow0 + r) * N + gcol;
                if (EPI == 0)      outFz[idx] = v * scale;
                else if (EPI == 1) outH[idx] = __float2bfloat16(v + biasSel[gcol]);
                else               outH[idx] = __float2bfloat16(__expf(v * scale));
            }
        }
    }
}

// ---------------- row sums of E[4096][8192] bf16 -> fp32 ----------------
__global__ __launch_bounds__(256) void rowsumE_k(const __hip_bfloat16* __restrict__ E,
                                                 float* __restrict__ rowsum) {
    int row = blockIdx.x;
    const ushortx8* p = (const ushortx8*)(E + (size_t)row * MSLOTS);
    float s = 0.f;
    #pragma unroll
    for (int c = 0; c < 4; c++) {
        ushortx8 x = p[threadIdx.x + c * 256];
        #pragma unroll
        for (int e = 0; e < 8; e++) s += b2f_bits(x[e]);
    }
    float t = blockReduceSum(s);
    if (threadIdx.x == 0) rowsum[row] = t;
}

// ---------------- sum 4 fp32 partials, scale by 1/rowsum -> out ----------------
__global__ __launch_bounds__(256) void reduce4_k(const float4* __restrict__ p,
                                                 const float* __restrict__ rowsum,
                                                 float4* __restrict__ out, int n4) {
    int i = blockIdx.x * 256 + threadIdx.x;
    if (i < n4) {
        float inv = 1.f / rowsum[i >> 8];          // HDIM/4 = 256 float4 per row
        float4 a = p[i], b = p[i + n4], c = p[i + 2 * n4], d = p[i + 3 * n4];
        float4 o;
        o.x = ((a.x + b.x) + (c.x + d.x)) * inv;
        o.y = ((a.y + b.y) + (c.y + d.y)) * inv;
        o.z = ((a.z + b.z) + (c.z + d.z)) * inv;
        o.w = ((a.w + b.w) + (c.w + d.w)) * inv;
        out[i] = o;
    }
}

// ---------------- launch ----------------
extern "C" void kernel_launch(void* const* d_in, const int* in_sizes, int n_in,
                              void* d_out, int out_size, void* d_ws, size_t ws_size,
                              hipStream_t stream) {
    const float* hidden = (const float*)d_in[0];   // [2,2048,1024]
    const float* membuf = (const float*)d_in[1];   // [8192,1024]
    const float* imp    = (const float*)d_in[2];   // [8192]
    const float* Wq     = (const float*)d_in[3];   // [1024,1024]
    const float* bq     = (const float*)d_in[4];   // [1024]
    const float* Wk     = (const float*)d_in[5];   // [1024,1024]
    const float* bk     = (const float*)d_in[6];   // [1024]
    const float* noise  = (const float*)d_in[7];   // [8192]

    char* ws = (char*)d_ws;
    size_t off = 0;
    auto alloc = [&](size_t bytes) -> void* {
        void* p = ws + off;
        off += (bytes + 255) & ~(size_t)255;
        return p;
    };
    // --- persistent region (front) ---
    float*          surprise = (float*)alloc(BS_CAND * 4);
    float*          skeys    = (float*)alloc(MSLOTS * 4);
    float*          rowsum   = (float*)alloc(BS_CAND * 4);
    int*            cand_ord = (int*)alloc(BS_CAND * 4);
    int*            slot_ord = (int*)alloc(MSLOTS * 4);
    int*            row_src  = (int*)alloc(MSLOTS * 4);
    __hip_bfloat16* Wqbf = (__hip_bfloat16*)alloc((size_t)HDIM * HDIM * 2);    // 2 MB
    __hip_bfloat16* Wkbf = (__hip_bfloat16*)alloc((size_t)HDIM * HDIM * 2);    // 2 MB
    __hip_bfloat16* BbfT = (__hip_bfloat16*)alloc((size_t)HDIM * MSLOTS * 2);  // 16 MB
    // --- Sbf region (64 MB), overlaid with Hbf (8 MB) + Bbf (16 MB), which are
    // CONTIGUOUS (A = [H; B] for the fused projection GEMM) and die before the
    // scores GEMM writes Sbf ---
    size_t s_base = off;
    __hip_bfloat16* Sbf = (__hip_bfloat16*)(ws + s_base);                      // 64 MB
    __hip_bfloat16* Hbf = (__hip_bfloat16*)(ws + s_base);                      //  8 MB
    __hip_bfloat16* Bbf = (__hip_bfloat16*)(ws + s_base + (size_t)BS_CAND * HDIM * 2);
    off = s_base + ((size_t)BS_CAND * MSLOTS * 2 + 255) & ~(size_t)255;
    // --- tail region: qbf+mkbf CONTIGUOUS (out = [q; mk]); PV partials (64 MB)
    // overlay them after the scores GEMM ---
    size_t t_base = off;
    __hip_bfloat16* qbf  = (__hip_bfloat16*)alloc((size_t)BS_CAND * HDIM * 2); // 8 MB
    __hip_bfloat16* mkbf = (__hip_bfloat16*)alloc((size_t)MSLOTS * HDIM * 2);  // 16 MB
    float*          part = (float*)(ws + t_base);       // 4 x 16 MB fp32 partials
    // peak usage = t_base + 64 MB  (~148 MB total)

    // 1) selection phase (+ hidden bf16 cast fused into the norm pass)
    norm_f2b_k<<<BS_CAND, 256, 0, stream>>>(hidden, surprise, Hbf);
    slot_keys_k<<<MSLOTS / 256, 256, 0, stream>>>(imp, noise, skeys, row_src);
    rank_k<1><<<BS_CAND, 256, 0, stream>>>(surprise, BS_CAND, cand_ord);
    rank_k<0><<<MSLOTS, 256, 0, stream>>>(skeys, MSLOTS, slot_ord);
    scatter_k<<<BS_CAND / 256, 256, 0, stream>>>(cand_ord, slot_ord, surprise, row_src);

    // 2) bf16 materialization
    f2b2_k<<<2 * (HDIM * HDIM / 4) / 256, 256, 0, stream>>>(Wq, Wqbf, Wk, Wkbf,
                                                            HDIM * HDIM / 4);
    build_b_k<<<MSLOTS, 256, 0, stream>>>(membuf, hidden, row_src, Bbf);
    transpose_k<<<dim3(HDIM / 64, MSLOTS / 64), 256, 0, stream>>>(Bbf, BbfT, MSLOTS, HDIM);

    // 3) fused projections: [q; mk] = [H; newbuf] @ {Wq,Wk}^T + {bq,bk}
    //    A rows 0..4095 -> Wq/bq, rows 4096..12287 -> Wk/bk (switch at bm=32)
    gemm_bt<1, 0><<<dim3(HDIM / 128, (BS_CAND + MSLOTS) / 128), 256, 0, stream>>>(
        Hbf, Wqbf, Wkbf, nullptr, qbf, bq, bk, BS_CAND / 128,
        BS_CAND + MSLOTS, HDIM, HDIM, HDIM, 1.f);
    // 4) E = bf16(exp((q @ mk^T)/32))  [4096,8192] — overwrites Hbf/Bbf region
    gemm_bt<2, 0><<<dim3(MSLOTS / 128, BS_CAND / 128), 256, 0, stream>>>(
        qbf, mkbf, nullptr, nullptr, Sbf, nullptr, nullptr, 1 << 30,
        BS_CAND, MSLOTS, HDIM, HDIM, 0.03125f);
    // 5) rowsum = row sums of E    -> fp32 [4096]
    rowsumE_k<<<BS_CAND, 256, 0, stream>>>(Sbf, rowsum);
    // 6) split-K PV: partial[z] = E @ newbuf over K-chunk z  (overlays qbf/mkbf)
    //    SWAP=1: bm on grid.x so all bn-blocks of one bm share an XCD (L2 reuse)
    gemm_bt<0, 1><<<dim3(BS_CAND / 128, HDIM / 128, PV_SPLIT), 256, 0, stream>>>(
        Sbf, BbfT, nullptr, part, nullptr, nullptr, nullptr, 1 << 30,
        BS_CAND, HDIM, MSLOTS, MSLOTS / PV_SPLIT, 1.f);
    // 7) out = (sum of 4 partials) / rowsum   -> fp32 [4096,1024]
    reduce4_k<<<(BS_CAND * HDIM / 4) / 256, 256, 0, stream>>>(
        (const float4*)part, rowsum, (float4*)d_out, BS_CAND * HDIM / 4);
}

// Round 9
// 366.923 us; speedup vs baseline: 1.2612x; 1.0417x over previous
//
#include <hip/hip_runtime.h>
#include <hip/hip_bf16.h>
#include <math.h>
#include <stdint.h>

typedef __attribute__((ext_vector_type(4))) float floatx4;
typedef __attribute__((ext_vector_type(8))) short shortx8;
typedef __attribute__((ext_vector_type(8))) unsigned short ushortx8;
typedef __attribute__((ext_vector_type(4))) unsigned short ushortx4;

#define BS_CAND 4096   // B*S
#define HDIM    1024
#define MSLOTS  8192
#define THRESH  64.0f
#define PV_SPLIT 4
#define PS_COLS 128    // 64 bn-blocks x 2 wave-parities

__device__ __forceinline__ unsigned short f2b_bits(float f) {
    __hip_bfloat16 b = __float2bfloat16(f);
    return *(unsigned short*)&b;
}
__device__ __forceinline__ float b2f_bits(unsigned short u) {
    return __uint_as_float(((unsigned)u) << 16);
}

// ---------------- reduction helper (blockDim == 256) ----------------
__device__ __forceinline__ float blockReduceSum(float x) {
    __shared__ float red[4];
    #pragma unroll
    for (int o = 32; o > 0; o >>= 1) x += __shfl_down(x, o, 64);
    int lane = threadIdx.x & 63, w = threadIdx.x >> 6;
    if (lane == 0) red[w] = x;
    __syncthreads();
    float s = red[0] + red[1] + red[2] + red[3];
    __syncthreads();
    return s;
}

// ------- merged prologue: norm+cast of hidden | slot keys | Wq/Wk cast -------
// blocks [0,4096): surprise + bf16 cast of hidden row
// blocks [4096,4128): slot keys & row_src init
// blocks [4128,6176): f2b of Wq (first 1024) / Wk (next 1024)
__global__ __launch_bounds__(256) void pre_k(const float* __restrict__ h,
                                             float* __restrict__ sur,
                                             __hip_bfloat16* __restrict__ Hbf,
                                             const float* __restrict__ imp,
                                             const float* __restrict__ noi,
                                             float* __restrict__ keys,
                                             int* __restrict__ row_src,
                                             const float* __restrict__ Wq,
                                             __hip_bfloat16* __restrict__ Wqbf,
                                             const float* __restrict__ Wk,
                                             __hip_bfloat16* __restrict__ Wkbf) {
    int b = blockIdx.x;
    if (b < BS_CAND) {
        float4 v = ((const float4*)(h + (size_t)b * HDIM))[threadIdx.x];
        ushortx4 o;
        o.x = f2b_bits(v.x); o.y = f2b_bits(v.y);
        o.z = f2b_bits(v.z); o.w = f2b_bits(v.w);
        ((ushortx4*)(Hbf + (size_t)b * HDIM))[threadIdx.x] = o;
        float s = v.x * v.x + v.y * v.y + v.z * v.z + v.w * v.w;
        float tot = blockReduceSum(s);
        if (threadIdx.x == 0) sur[b] = 2.0f * sqrtf(tot);
    } else if (b < BS_CAND + MSLOTS / 256) {
        int i = (b - BS_CAND) * 256 + threadIdx.x;
        keys[i] = imp[i] + noi[i] * 1e-6f;
        row_src[i] = -1;
    } else {
        int w = b - (BS_CAND + MSLOTS / 256);          // 0..2047
        const float* in = (w < 1024) ? Wq : Wk;
        __hip_bfloat16* out = (w < 1024) ? Wqbf : Wkbf;
        int j = (w & 1023) * 256 + threadIdx.x;        // float4 index
        float4 v = ((const float4*)in)[j];
        ushortx4 o;
        o.x = f2b_bits(v.x); o.y = f2b_bits(v.y);
        o.z = f2b_bits(v.z); o.w = f2b_bits(v.w);
        ((ushortx4*)out)[j] = o;
    }
}

// ---------------- merged ranks: one BLOCK per element ----------------
// blocks [0,4096): rank sur[b] DESC among 4096 -> cand_ord
// blocks [4096,12288): rank keys[b-4096] ASC among 8192 -> slot_ord
__global__ __launch_bounds__(256) void ranks_k(const float* __restrict__ sur,
                                               int* __restrict__ cand_ord,
                                               const float* __restrict__ keys,
                                               int* __restrict__ slot_ord) {
    int b = blockIdx.x;
    if (b < BS_CAND) {
        float ki = sur[b];
        float cnt = 0.f;
        for (int j = threadIdx.x; j < BS_CAND; j += 256) {
            float kj = sur[j];
            cnt += ((kj > ki) || (kj == ki && j < b)) ? 1.f : 0.f;
        }
        float r = blockReduceSum(cnt);
        if (threadIdx.x == 0) cand_ord[(int)r] = b;
    } else {
        int i = b - BS_CAND;
        float ki = keys[i];
        float cnt = 0.f;
        for (int j = threadIdx.x; j < MSLOTS; j += 256) {
            float kj = keys[j];
            cnt += ((kj < ki) || (kj == ki && j < i)) ? 1.f : 0.f;
        }
        float r = blockReduceSum(cnt);
        if (threadIdx.x == 0) slot_ord[(int)r] = i;
    }
}

// ---------------- scatter: rank-i candidate -> rank-i least-important slot ----
__global__ __launch_bounds__(256) void scatter_k(const int* __restrict__ cand_order,
                                                 const int* __restrict__ slot_order,
                                                 const float* __restrict__ sur,
                                                 int* __restrict__ row_src) {
    int i = blockIdx.x * 256 + threadIdx.x;   // i < BS_CAND
    int c = cand_order[i];
    if (sur[c] > THRESH) row_src[slot_order[i]] = c;
}

// ---------------- build updated buffer (bf16), 4 elems/thread -------------
__global__ __launch_bounds__(256) void build_b_k(const float* __restrict__ mem,
                                                 const float* __restrict__ hid,
                                                 const int* __restrict__ src,
                                                 __hip_bfloat16* __restrict__ B) {
    int m = blockIdx.x;
    int s = src[m];
    const float4* r = (const float4*)((s < 0) ? (mem + (size_t)m * HDIM)
                                              : (hid + (size_t)s * HDIM));
    float4 v = r[threadIdx.x];                 // HDIM/4 == 256 == blockDim
    ushortx4 o;
    o.x = f2b_bits(v.x); o.y = f2b_bits(v.y);
    o.z = f2b_bits(v.z); o.w = f2b_bits(v.w);
    ((ushortx4*)(B + (size_t)m * HDIM))[threadIdx.x] = o;
}

// ---------------- bf16 transpose [R][C] -> [C][R] ----------------
__global__ __launch_bounds__(256) void transpose_k(const __hip_bfloat16* __restrict__ in,
                                                   __hip_bfloat16* __restrict__ out,
                                                   int R, int C) {
    __shared__ __hip_bfloat16 t[64][65];
    int cb = blockIdx.x * 64, rb = blockIdx.y * 64;
    int tx = threadIdx.x & 63, ty = threadIdx.x >> 6;
    #pragma unroll
    for (int k = 0; k < 16; k++) {
        int r = ty * 16 + k;
        t[r][tx] = in[(size_t)(rb + r) * C + cb + tx];
    }
    __syncthreads();
    #pragma unroll
    for (int k = 0; k < 16; k++) {
        int c = ty * 16 + k;
        out[(size_t)(cb + c) * R + rb + tx] = t[tx][c];
    }
}

// ---------------- async global->LDS helper ----------------
__device__ __forceinline__ void load_lds16(const __hip_bfloat16* g, __hip_bfloat16* l) {
    __builtin_amdgcn_global_load_lds(
        (const __attribute__((address_space(1))) void*)g,
        (__attribute__((address_space(3))) void*)l, 16, 0, 0);
}

// ---------------- BT-GEMM: C[M,N] = A[M,K] * Bt[N,K]^T ----------
// LDS tiles as two 128x32 planes (row = 64 B = 16 bank-words): ds_read_b128
// fragment reads hit all 32 banks uniformly. SWAP=1: bm on blockIdx.x (XCD
// locality for A re-reads).
// EPI 1: outH[idx] = bf16(acc + biasSel[col]); Bt/bias switch at block-row rows0b
//        (fused q/mk projection: A = [H; B] contiguous, out = [q; mk] contiguous)
// EPI 2: outH[idx] = bf16(exp(acc*scale)); per-wave 64-col strip sums -> ps
//        (softmax numerator; |S|<=~3 so max-subtraction unnecessary in fp32)
// EPI 4: outH[z*M*N + idx] = bf16(acc * scale)   (bf16 split-K partial)
template <int EPI, int SWAP>
__global__ __launch_bounds__(256) void gemm_bt(const __hip_bfloat16* __restrict__ A,
                                               const __hip_bfloat16* __restrict__ Bt,
                                               const __hip_bfloat16* __restrict__ Bt2,
                                               __hip_bfloat16* __restrict__ outH,
                                               const float* __restrict__ bias,
                                               const float* __restrict__ bias2,
                                               float* __restrict__ ps,
                                               int rows0b,
                                               int M, int N, int K, int ksplit,
                                               float scale) {
    __shared__ alignas(16) __hip_bfloat16 Asm[2][128 * 32];   // plane p: k-sub [p*32,p*32+32)
    __shared__ alignas(16) __hip_bfloat16 Bsm[2][128 * 32];
    const int tid = threadIdx.x;
    const int wave = tid >> 6, lane = tid & 63;
    const int bm = SWAP ? blockIdx.x : blockIdx.y;
    const int bn = SWAP ? blockIdx.y : blockIdx.x;
    const int kb = blockIdx.z * ksplit, ke = kb + ksplit;
    const int wr = (wave >> 1) * 64, wc = (wave & 1) * 64;
    const int lm = lane & 15, lq = lane >> 4;

    const __hip_bfloat16* BtSel = (EPI == 1 && bm >= rows0b) ? Bt2 : Bt;
    const float* biasSel = (EPI == 1 && bm >= rows0b) ? bias2 : bias;

    floatx4 acc[4][4];
    #pragma unroll
    for (int i = 0; i < 4; i++)
        #pragma unroll
        for (int j = 0; j < 4; j++) acc[i][j] = {0.f, 0.f, 0.f, 0.f};

    const __hip_bfloat16* Abase = A + (size_t)bm * 128 * K;
    const __hip_bfloat16* Bbase = BtSel + (size_t)bn * 128 * K;

    for (int k0 = kb; k0 < ke; k0 += 64) {
        #pragma unroll
        for (int t = 0; t < 4; t++) {
            int g = wave * 4 + t;              // call id 0..15
            int p = g >> 3;                    // plane
            int pcb = (g & 7) << 6;            // plane-chunk base
            int pc = pcb + lane;               // plane chunk 0..511
            int row = pc >> 2, cc = pc & 3;    // 4 x 16B chunks per 64B plane row
            load_lds16(Abase + (size_t)row * K + k0 + p * 32 + cc * 8,
                       &Asm[p][pcb * 8]);
        }
        #pragma unroll
        for (int t = 0; t < 4; t++) {
            int g = wave * 4 + t;
            int p = g >> 3;
            int pcb = (g & 7) << 6;
            int pc = pcb + lane;
            int row = pc >> 2, cc = pc & 3;
            load_lds16(Bbase + (size_t)row * K + k0 + p * 32 + cc * 8,
                       &Bsm[p][pcb * 8]);
        }
        __syncthreads();
        #pragma unroll
        for (int ks = 0; ks < 2; ks++) {
            shortx8 af[4], bfr[4];
            #pragma unroll
            for (int i = 0; i < 4; i++)
                af[i] = *(const shortx8*)(&Asm[ks][(wr + i * 16 + lm) * 32 + lq * 8]);
            #pragma unroll
            for (int j = 0; j < 4; j++)
                bfr[j] = *(const shortx8*)(&Bsm[ks][(wc + j * 16 + lm) * 32 + lq * 8]);
            #pragma unroll
            for (int i = 0; i < 4; i++)
                #pragma unroll
                for (int j = 0; j < 4; j++)
                    acc[i][j] = __builtin_amdgcn_mfma_f32_16x16x32_bf16(af[i], bfr[j],
                                                                        acc[i][j], 0, 0, 0);
        }
        __syncthreads();
    }

    if (EPI == 2) {
        // E = bf16(exp(S)); ps[row][bn*2 + waveparity] = sum of this wave's 64 cols
        #pragma unroll
        for (int i = 0; i < 4; i++) {
            int grow0 = bm * 128 + wr + i * 16 + lq * 4;
            #pragma unroll
            for (int r = 0; r < 4; r++) {
                float rs = 0.f;
                #pragma unroll
                for (int j = 0; j < 4; j++) {
                    int gcol = bn * 128 + wc + j * 16 + lm;
                    float e = __expf(acc[i][j][r] * scale);
                    unsigned short eb = f2b_bits(e);
                    ((unsigned short*)outH)[(size_t)(grow0 + r) * N + gcol] = eb;
                    rs += b2f_bits(eb);
                }
                rs += __shfl_xor(rs, 1, 64);
                rs += __shfl_xor(rs, 2, 64);
                rs += __shfl_xor(rs, 4, 64);
                rs += __shfl_xor(rs, 8, 64);
                if (lm == 0)
                    ps[(size_t)(grow0 + r) * PS_COLS + bn * 2 + (wave & 1)] = rs;
            }
        }
    } else {
        __hip_bfloat16* outHz = outH + ((EPI == 4) ? (size_t)blockIdx.z * M * N : 0);
        #pragma unroll
        for (int i = 0; i < 4; i++) {
            int grow0 = bm * 128 + wr + i * 16 + lq * 4;
            #pragma unroll
            for (int j = 0; j < 4; j++) {
                int gcol = bn * 128 + wc + j * 16 + lm;
                #pragma unroll
                for (int r = 0; r < 4; r++) {
                    float v = acc[i][j][r];
                    size_t idx = (size_t)(grow0 + r) * N + gcol;
                    if (EPI == 1) outHz[idx] = __float2bfloat16(v + biasSel[gcol]);
                    else          outHz[idx] = __float2bfloat16(v * scale);
                }
            }
        }
    }
}

// ------- final: out[row] = (sum of bf16 partials) / (sum of ps[row][*]) -------
// one block per row; 256 threads = 256 float4 = HDIM
__global__ __launch_bounds__(256) void reduce4_k(const ushortx4* __restrict__ part,
                                                 const float* __restrict__ ps,
                                                 float4* __restrict__ out) {
    int row = blockIdx.x;
    float s = 0.f;
    if (threadIdx.x < PS_COLS) s = ps[(size_t)row * PS_COLS + threadIdx.x];
    float tot = blockReduceSum(s);
    float inv = 1.f / tot;
    size_t base = (size_t)row * (HDIM / 4) + threadIdx.x;
    const size_t stride = (size_t)BS_CAND * (HDIM / 4);
    float4 o = {0.f, 0.f, 0.f, 0.f};
    #pragma unroll
    for (int z = 0; z < PV_SPLIT; z++) {
        ushortx4 p = part[base + (size_t)z * stride];
        o.x += b2f_bits(p.x); o.y += b2f_bits(p.y);
        o.z += b2f_bits(p.z); o.w += b2f_bits(p.w);
    }
    o.x *= inv; o.y *= inv; o.z *= inv; o.w *= inv;
    out[(size_t)row * (HDIM / 4) + threadIdx.x] = o;
}

// ---------------- launch ----------------
extern "C" void kernel_launch(void* const* d_in, const int* in_sizes, int n_in,
                              void* d_out, int out_size, void* d_ws, size_t ws_size,
                              hipStream_t stream) {
    const float* hidden = (const float*)d_in[0];   // [2,2048,1024]
    const float* membuf = (const float*)d_in[1];   // [8192,1024]
    const float* imp    = (const float*)d_in[2];   // [8192]
    const float* Wq     = (const float*)d_in[3];   // [1024,1024]
    const float* bq     = (const float*)d_in[4];   // [1024]
    const float* Wk     = (const float*)d_in[5];   // [1024,1024]
    const float* bk     = (const float*)d_in[6];   // [1024]
    const float* noise  = (const float*)d_in[7];   // [8192]

    char* ws = (char*)d_ws;
    size_t off = 0;
    auto alloc = [&](size_t bytes) -> void* {
        void* p = ws + off;
        off += (bytes + 255) & ~(size_t)255;
        return p;
    };
    // --- persistent region (front) ---
    float*          surprise = (float*)alloc(BS_CAND * 4);
    float*          skeys    = (float*)alloc(MSLOTS * 4);
    float*          ps       = (float*)alloc((size_t)BS_CAND * PS_COLS * 4);   // 2 MB
    int*            cand_ord = (int*)alloc(BS_CAND * 4);
    int*            slot_ord = (int*)alloc(MSLOTS * 4);
    int*            row_src  = (int*)alloc(MSLOTS * 4);
    __hip_bfloat16* Wqbf = (__hip_bfloat16*)alloc((size_t)HDIM * HDIM * 2);    // 2 MB
    __hip_bfloat16* Wkbf = (__hip_bfloat16*)alloc((size_t)HDIM * HDIM * 2);    // 2 MB
    __hip_bfloat16* BbfT = (__hip_bfloat16*)alloc((size_t)HDIM * MSLOTS * 2);  // 16 MB
    // --- Sbf region (64 MB), overlaid with Hbf (8 MB) + Bbf (16 MB), which are
    // CONTIGUOUS (A = [H; B] for the fused projection GEMM) and die before the
    // scores GEMM writes Sbf ---
    size_t s_base = off;
    __hip_bfloat16* Sbf = (__hip_bfloat16*)(ws + s_base);                      // 64 MB
    __hip_bfloat16* Hbf = (__hip_bfloat16*)(ws + s_base);                      //  8 MB
    __hip_bfloat16* Bbf = (__hip_bfloat16*)(ws + s_base + (size_t)BS_CAND * HDIM * 2);
    off = s_base + ((size_t)BS_CAND * MSLOTS * 2 + 255) & ~(size_t)255;
    // --- tail region: qbf+mkbf CONTIGUOUS (out = [q; mk]); bf16 PV partials
    // (4 x 8 MB) overlay them after the scores GEMM ---
    size_t t_base = off;
    __hip_bfloat16* qbf  = (__hip_bfloat16*)alloc((size_t)BS_CAND * HDIM * 2); // 8 MB
    __hip_bfloat16* mkbf = (__hip_bfloat16*)alloc((size_t)MSLOTS * HDIM * 2);  // 16 MB
    __hip_bfloat16* part = (__hip_bfloat16*)(ws + t_base);  // 4 x 8 MB bf16 partials
    // peak usage = t_base + 32 MB  (~116 MB total)

    // 1) merged prologue: hidden norm+cast | slot keys | Wq/Wk cast
    pre_k<<<BS_CAND + MSLOTS / 256 + 2048, 256, 0, stream>>>(
        hidden, surprise, Hbf, imp, noise, skeys, row_src, Wq, Wqbf, Wk, Wkbf);
    // 2) both rankings in one launch
    ranks_k<<<BS_CAND + MSLOTS, 256, 0, stream>>>(surprise, cand_ord, skeys, slot_ord);
    scatter_k<<<BS_CAND / 256, 256, 0, stream>>>(cand_ord, slot_ord, surprise, row_src);
    // 3) updated memory buffer + its transpose
    build_b_k<<<MSLOTS, 256, 0, stream>>>(membuf, hidden, row_src, Bbf);
    transpose_k<<<dim3(HDIM / 64, MSLOTS / 64), 256, 0, stream>>>(Bbf, BbfT, MSLOTS, HDIM);
    // 4) fused projections: [q; mk] = [H; newbuf] @ {Wq,Wk}^T + {bq,bk}
    gemm_bt<1, 0><<<dim3(HDIM / 128, (BS_CAND + MSLOTS) / 128), 256, 0, stream>>>(
        Hbf, Wqbf, Wkbf, qbf, bq, bk, nullptr, BS_CAND / 128,
        BS_CAND + MSLOTS, HDIM, HDIM, HDIM, 1.f);
    // 5) E = bf16(exp((q @ mk^T)/32)) + per-wave strip sums into ps
    gemm_bt<2, 0><<<dim3(MSLOTS / 128, BS_CAND / 128), 256, 0, stream>>>(
        qbf, mkbf, nullptr, Sbf, nullptr, nullptr, ps, 1 << 30,
        BS_CAND, MSLOTS, HDIM, HDIM, 0.03125f);
    // 6) split-K PV: bf16 partial[z] = E @ newbuf over K-chunk z (overlays qbf/mkbf)
    //    SWAP=1: bm on grid.x so all bn-blocks of one bm share an XCD (L2 reuse)
    gemm_bt<4, 1><<<dim3(BS_CAND / 128, HDIM / 128, PV_SPLIT), 256, 0, stream>>>(
        Sbf, BbfT, nullptr, part, nullptr, nullptr, nullptr, 1 << 30,
        BS_CAND, HDIM, MSLOTS, MSLOTS / PV_SPLIT, 1.f);
    // 7) out = (sum of 4 bf16 partials) / rowsum(ps)   -> fp32 [4096,1024]
    reduce4_k<<<BS_CAND, 256, 0, stream>>>((const ushortx4*)part, ps, (float4*)d_out);
}